// Round 1
// baseline (129.041 us; speedup 1.0000x reference)
//
#include <hip/hip_runtime.h>

#define T_TOTAL 4194304
#define S 16                      // outputs per thread
#define K 128                     // warmup steps (A^K negligible)
#define NTHREADS 256
#define BLOCK_T (NTHREADS * S)    // 4096 outputs per block
#define WSEG (K / S)              // 8 warmup segments
#define NSEG (NTHREADS + WSEG)    // 264 segments staged per block
#define NSEG_PAD (NSEG + 1)       // 265 (pad: break power-of-2 row stride)
#define NSTAGE (NSEG * S)         // 4224 timesteps staged

__global__ __launch_bounds__(NTHREADS)
void pinn_rnn_kernel(const float* __restrict__ x0p,
                     const float* __restrict__ u,
                     const float* __restrict__ td,
                     const float* __restrict__ WA,
                     const float* __restrict__ bA,
                     const float* __restrict__ WB,
                     const float* __restrict__ bB,
                     float* __restrict__ out)
{
    // Transposed layout [j][seg]: at inner iteration j, lane `tid` reads
    // column tid -> lane-stride-1 -> conflict-free. Naive [t] layout would
    // be lane-stride-16 floats = 32-way bank conflict.
    __shared__ float2 lv[S][NSEG_PAD];   // v_t = W_B u_t + bA + bB
    __shared__ float2 ls[S][NSEG_PAD];   // s_t = u0*dt * [cos u1, sin u1]

    const int tid = threadIdx.x;
    const int B0  = blockIdx.x * BLOCK_T;

    const float a00 = WA[0], a01 = WA[1], a10 = WA[2], a11 = WA[3];
    const float w00 = WB[0], w01 = WB[1], w10 = WB[2], w11 = WB[3];
    const float bc0 = bA[0] + bB[0];
    const float bc1 = bA[1] + bB[1];

    const float* u0 = u;
    const float* u1 = u + T_TOTAL;

    // ---- stage window [B0-K, B0+BLOCK_T) into LDS (coalesced) ----
    for (int i = tid; i < NSTAGE; i += NTHREADS) {
        int t = B0 - K + i;
        float ua = 0.f, ub = 0.f, dtv = 0.f;
        if (t >= 0) { ua = u0[t]; ub = u1[t]; dtv = td[t]; }
        float v0 = fmaf(w00, ua, fmaf(w01, ub, bc0));
        float v1 = fmaf(w10, ua, fmaf(w11, ub, bc1));
        float c = ua * dtv;
        float sn, cs;
        __sincosf(ub, &sn, &cs);
        int seg = i >> 4, j = i & (S - 1);
        lv[j][seg] = make_float2(v0, v1);
        ls[j][seg] = make_float2(c * cs, c * sn);
    }
    __syncthreads();

    // ---- per-thread windowed recurrence ----
    const int aG  = B0 + tid * S;            // first output timestep
    const int warm = (aG < K) ? aG : K;
    float x0v, x1v;
    if (aG <= K) { x0v = x0p[0]; x1v = x0p[1]; }   // exact start at t=0
    else         { x0v = 0.f;   x1v = 0.f;  }      // A^K * err -> negligible

    // warmup: v-only steps (8B LDS reads)
    int idx = (WSEG + tid) * S - warm;       // t_local of warmup start
    for (int m = 0; m < warm; ++m) {
        float2 v = lv[idx & (S - 1)][idx >> 4];
        float nx0 = fmaf(a00, x0v, fmaf(a01, x1v, v.x));
        float nx1 = fmaf(a10, x0v, fmaf(a11, x1v, v.y));
        x0v = nx0; x1v = nx1;
        ++idx;
    }

    // output steps: this thread's 16 outputs live in one segment column
    const int seg = WSEG + tid;
    float2* outp = (float2*)out;
    #pragma unroll
    for (int j = 0; j < S; ++j) {
        float2 v = lv[j][seg];
        float2 s = ls[j][seg];
        float nx0 = fmaf(a00, x0v, fmaf(a01, x1v, v.x));
        float nx1 = fmaf(a10, x0v, fmaf(a11, x1v, v.y));
        outp[aG + j] = make_float2(x0v + s.x - nx0, x1v + s.y - nx1);
        x0v = nx0; x1v = nx1;
    }
}

extern "C" void kernel_launch(void* const* d_in, const int* in_sizes, int n_in,
                              void* d_out, int out_size, void* d_ws, size_t ws_size,
                              hipStream_t stream) {
    const float* x0p = (const float*)d_in[0];
    const float* u   = (const float*)d_in[1];
    const float* td  = (const float*)d_in[2];
    const float* WA  = (const float*)d_in[3];
    const float* bA  = (const float*)d_in[4];
    const float* WB  = (const float*)d_in[5];
    const float* bB  = (const float*)d_in[6];
    float* outp = (float*)d_out;

    dim3 grid(T_TOTAL / BLOCK_T);   // 1024 blocks
    dim3 block(NTHREADS);
    pinn_rnn_kernel<<<grid, block, 0, stream>>>(x0p, u, td, WA, bA, WB, bB, outp);
}

// Round 2
// 125.154 us; speedup vs baseline: 1.0311x; 1.0311x over previous
//
#include <hip/hip_runtime.h>

#define T_TOTAL 4194304
#define S 16                       // outputs per thread (one segment)
#define NTHREADS 256
#define BLOCK_T (NTHREADS * S)     // 4096 outputs per block
#define HALO_SEG 4                 // 4 halo segments = 64 warmup steps; A^64 ~ 1e-8
#define NSEG (NTHREADS + HALO_SEG) // 260 segments staged
#define NSEG_PAD (NSEG + 1)        // 261
#define NSTAGE (NSEG * S)          // 4160 timesteps staged

struct M22 { float m00, m01, m10, m11; };
__device__ __forceinline__ M22 mmul(const M22& X, const M22& Y) {
    M22 r;
    r.m00 = fmaf(X.m00, Y.m00, X.m01 * Y.m10);
    r.m01 = fmaf(X.m00, Y.m01, X.m01 * Y.m11);
    r.m10 = fmaf(X.m10, Y.m00, X.m11 * Y.m10);
    r.m11 = fmaf(X.m10, Y.m01, X.m11 * Y.m11);
    return r;
}

__global__ __launch_bounds__(NTHREADS)
void pinn_rnn_kernel(const float* __restrict__ x0p,
                     const float* __restrict__ u,
                     const float* __restrict__ td,
                     const float* __restrict__ WA,
                     const float* __restrict__ bA,
                     const float* __restrict__ WB,
                     const float* __restrict__ bB,
                     float* __restrict__ out)
{
    // Transposed [j][seg] layout: at unrolled step j, lane tid reads column
    // tid+HALO_SEG -> lane-stride-1 float2 -> conflict-free (2-way is free).
    __shared__ float2 lu [S][NSEG_PAD];   // (u0, u1)
    __shared__ float  ldt[S][NSEG_PAD];   // dt
    __shared__ float2 lc [NSEG];          // per-segment zero-state response c

    const int tid = threadIdx.x;
    const int B0  = blockIdx.x * BLOCK_T;

    const float a00 = WA[0], a01 = WA[1], a10 = WA[2], a11 = WA[3];
    const float w00 = WB[0], w01 = WB[1], w10 = WB[2], w11 = WB[3];
    const float bc0 = bA[0] + bB[0];
    const float bc1 = bA[1] + bB[1];

    const float* u0 = u;
    const float* u1 = u + T_TOTAL;

    // ---- stage raw (u0,u1,dt) window [B0-64, B0+4096) into LDS, coalesced ----
    for (int i = tid; i < NSTAGE; i += NTHREADS) {
        int t = B0 - HALO_SEG * S + i;
        float ua = 0.f, ub = 0.f, dtv = 0.f;
        if (t >= 0) { ua = u0[t]; ub = u1[t]; dtv = td[t]; }
        int seg = i >> 4, j = i & (S - 1);
        lu [j][seg] = make_float2(ua, ub);
        ldt[j][seg] = dtv;
    }

    // ---- powers of A (all threads compute identically; ~50 fma) ----
    M22 A  = { a00, a01, a10, a11 };
    M22 A2 = mmul(A,  A );
    M22 A4 = mmul(A2, A2);
    M22 A8 = mmul(A4, A4);
    M22 M  = mmul(A8, A8);   // A^16
    M22 M2 = mmul(M,  M );   // A^32
    M22 M3 = mmul(M2, M );   // A^48

    __syncthreads();

    const int g = tid + HALO_SEG;   // this thread's output segment

    // ---- phase 1: zero-state response c for own segment (fully unrolled) ----
    {
        float x0v = 0.f, x1v = 0.f;
        #pragma unroll
        for (int j = 0; j < S; ++j) {
            float2 uu = lu[j][g];
            float v0 = fmaf(w00, uu.x, fmaf(w01, uu.y, bc0));
            float v1 = fmaf(w10, uu.x, fmaf(w11, uu.y, bc1));
            float n0 = fmaf(a00, x0v, fmaf(a01, x1v, v0));
            float n1 = fmaf(a10, x0v, fmaf(a11, x1v, v1));
            x0v = n0; x1v = n1;
        }
        lc[g] = make_float2(x0v, x1v);
    }
    // halo segments: 4 extra c's per block (threads 0..3 do double duty)
    if (tid < HALO_SEG) {
        if (blockIdx.x == 0) {
            lc[tid] = make_float2(0.f, 0.f);   // nothing exists before t=0
        } else {
            float x0v = 0.f, x1v = 0.f;
            #pragma unroll
            for (int j = 0; j < S; ++j) {
                float2 uu = lu[j][tid];
                float v0 = fmaf(w00, uu.x, fmaf(w01, uu.y, bc0));
                float v1 = fmaf(w10, uu.x, fmaf(w11, uu.y, bc1));
                float n0 = fmaf(a00, x0v, fmaf(a01, x1v, v0));
                float n1 = fmaf(a10, x0v, fmaf(a11, x1v, v1));
                x0v = n0; x1v = n1;
            }
            lc[tid] = make_float2(x0v, x1v);
        }
    }
    __syncthreads();

    // ---- incoming state: x_in = c_{g-1} + M c_{g-2} + M2 c_{g-3} + M3 c_{g-4} ----
    float2 c1 = lc[g - 1], c2 = lc[g - 2], c3 = lc[g - 3], c4 = lc[g - 4];
    float xi0 = c1.x
              + fmaf(M.m00,  c2.x, M.m01  * c2.y)
              + fmaf(M2.m00, c3.x, M2.m01 * c3.y)
              + fmaf(M3.m00, c4.x, M3.m01 * c4.y);
    float xi1 = c1.y
              + fmaf(M.m10,  c2.x, M.m11  * c2.y)
              + fmaf(M2.m10, c3.x, M2.m11 * c3.y)
              + fmaf(M3.m10, c4.x, M3.m11 * c4.y);

    // block 0: first 4 threads carry the exact A^(16*tid) * x_0 term
    if (blockIdx.x == 0 && tid < HALO_SEG) {
        float X0 = x0p[0], X1 = x0p[1];
        M22 P;
        if      (tid == 0) { P.m00 = 1.f; P.m01 = 0.f; P.m10 = 0.f; P.m11 = 1.f; }
        else if (tid == 1) P = M;
        else if (tid == 2) P = M2;
        else               P = M3;
        xi0 += fmaf(P.m00, X0, P.m01 * X1);
        xi1 += fmaf(P.m10, X0, P.m11 * X1);
    }

    // ---- phase 2: rerun segment from x_in, emit outputs (fully unrolled) ----
    float x0v = xi0, x1v = xi1;
    const int aG = B0 + tid * S;
    float2* outp = (float2*)out;
    #pragma unroll
    for (int j = 0; j < S; ++j) {
        float2 uu = lu[j][g];
        float dtv = ldt[j][g];
        float v0 = fmaf(w00, uu.x, fmaf(w01, uu.y, bc0));
        float v1 = fmaf(w10, uu.x, fmaf(w11, uu.y, bc1));
        float n0 = fmaf(a00, x0v, fmaf(a01, x1v, v0));
        float n1 = fmaf(a10, x0v, fmaf(a11, x1v, v1));
        float cc = uu.x * dtv;
        float sn, cs;
        __sincosf(uu.y, &sn, &cs);
        outp[aG + j] = make_float2(fmaf(cc, cs, x0v) - n0,
                                   fmaf(cc, sn, x1v) - n1);
        x0v = n0; x1v = n1;
    }
}

extern "C" void kernel_launch(void* const* d_in, const int* in_sizes, int n_in,
                              void* d_out, int out_size, void* d_ws, size_t ws_size,
                              hipStream_t stream) {
    const float* x0p = (const float*)d_in[0];
    const float* u   = (const float*)d_in[1];
    const float* td  = (const float*)d_in[2];
    const float* WA  = (const float*)d_in[3];
    const float* bA  = (const float*)d_in[4];
    const float* WB  = (const float*)d_in[5];
    const float* bB  = (const float*)d_in[6];
    float* outp = (float*)d_out;

    dim3 grid(T_TOTAL / BLOCK_T);   // 1024 blocks
    dim3 block(NTHREADS);
    pinn_rnn_kernel<<<grid, block, 0, stream>>>(x0p, u, td, WA, bA, WB, bB, outp);
}

// Round 3
// 106.631 us; speedup vs baseline: 1.2102x; 1.1737x over previous
//
#include <hip/hip_runtime.h>

#define T_TOTAL 4194304
#define S 16                       // timesteps per thread (one segment)
#define NTHREADS 256
#define BLOCK_T (NTHREADS * S)     // 4096 timesteps per block
#define HALO_SEG 4                 // 64 warmup steps; ||A^64|| ~ 1e-8
#define NSEG (NTHREADS + HALO_SEG) // 260

struct M22 { float m00, m01, m10, m11; };
__device__ __forceinline__ M22 mmul(const M22& X, const M22& Y) {
    M22 r;
    r.m00 = fmaf(X.m00, Y.m00, X.m01 * Y.m10);
    r.m01 = fmaf(X.m00, Y.m01, X.m01 * Y.m11);
    r.m10 = fmaf(X.m10, Y.m00, X.m11 * Y.m10);
    r.m11 = fmaf(X.m10, Y.m01, X.m11 * Y.m11);
    return r;
}

struct alignas(16) F16 { float f[16]; };
__device__ __forceinline__ void load16(F16& d, const float* __restrict__ p) {
    const float4* q = (const float4*)p;     // p is 64B-aligned (t0 % 16 == 0)
    float4 a0 = q[0], a1 = q[1], a2 = q[2], a3 = q[3];
    *(float4*)&d.f[0]  = a0;
    *(float4*)&d.f[4]  = a1;
    *(float4*)&d.f[8]  = a2;
    *(float4*)&d.f[12] = a3;
}

__global__ __launch_bounds__(NTHREADS, 4)   // 4 blocks/CU: LDS 34.8KB, VGPR<=128
void pinn_rnn_kernel(const float* __restrict__ x0p,
                     const float* __restrict__ u,
                     const float* __restrict__ td,
                     const float* __restrict__ WA,
                     const float* __restrict__ bA,
                     const float* __restrict__ WB,
                     const float* __restrict__ bB,
                     float* __restrict__ out)
{
    __shared__ float2 lc[NSEG];        // per-segment zero-state response (2 KB)
    __shared__ float2 lout[BLOCK_T];   // xor-swizzled output transpose (32 KB)

    const int tid = threadIdx.x;
    const int B0  = blockIdx.x * BLOCK_T;

    const float a00 = WA[0], a01 = WA[1], a10 = WA[2], a11 = WA[3];
    const float w00 = WB[0], w01 = WB[1], w10 = WB[2], w11 = WB[3];
    const float bc0 = bA[0] + bB[0];
    const float bc1 = bA[1] + bB[1];

    const float* u0 = u;
    const float* u1 = u + T_TOTAL;

    // ---- own segment: direct per-lane-chunk loads into registers ----
    const int t0 = B0 + tid * S;
    F16 U0, U1, DT;
    load16(U0, u0 + t0);
    load16(U1, u1 + t0);
    load16(DT, td + t0);

    // ---- powers of A (uniform, ~30 fma) ----
    M22 A   = { a00, a01, a10, a11 };
    M22 A2  = mmul(A,  A );
    M22 A4  = mmul(A2, A2);
    M22 A8  = mmul(A4, A4);
    M22 M   = mmul(A8, A8);   // A^16
    M22 Mp2 = mmul(M,  M );   // A^32
    M22 Mp3 = mmul(Mp2, M);   // A^48

    // ---- phase 1: zero-state response c for own segment ----
    {
        float x0v = 0.f, x1v = 0.f;
        #pragma unroll
        for (int j = 0; j < S; ++j) {
            float v0 = fmaf(w00, U0.f[j], fmaf(w01, U1.f[j], bc0));
            float v1 = fmaf(w10, U0.f[j], fmaf(w11, U1.f[j], bc1));
            float n0 = fmaf(a00, x0v, fmaf(a01, x1v, v0));
            float n1 = fmaf(a10, x0v, fmaf(a11, x1v, v1));
            x0v = n0; x1v = n1;
        }
        lc[tid + HALO_SEG] = make_float2(x0v, x1v);
    }
    // halo segments (4 per block); block 0 has nothing before t=0
    if (tid < HALO_SEG) {
        float2 ch = make_float2(0.f, 0.f);
        if (blockIdx.x != 0) {
            const int th = B0 - HALO_SEG * S + tid * S;
            F16 H0, H1;
            load16(H0, u0 + th);
            load16(H1, u1 + th);
            float x0v = 0.f, x1v = 0.f;
            #pragma unroll
            for (int j = 0; j < S; ++j) {
                float v0 = fmaf(w00, H0.f[j], fmaf(w01, H1.f[j], bc0));
                float v1 = fmaf(w10, H0.f[j], fmaf(w11, H1.f[j], bc1));
                float n0 = fmaf(a00, x0v, fmaf(a01, x1v, v0));
                float n1 = fmaf(a10, x0v, fmaf(a11, x1v, v1));
                x0v = n0; x1v = n1;
            }
            ch = make_float2(x0v, x1v);
        }
        lc[tid] = ch;
    }
    __syncthreads();

    // ---- incoming state: x_in = c_{g-1} + M c_{g-2} + M^2 c_{g-3} + M^3 c_{g-4} ----
    float2 c1 = lc[tid + 3], c2 = lc[tid + 2], c3 = lc[tid + 1], c4 = lc[tid];
    float xi0 = c1.x
              + fmaf(M.m00,   c2.x, M.m01   * c2.y)
              + fmaf(Mp2.m00, c3.x, Mp2.m01 * c3.y)
              + fmaf(Mp3.m00, c4.x, Mp3.m01 * c4.y);
    float xi1 = c1.y
              + fmaf(M.m10,   c2.x, M.m11   * c2.y)
              + fmaf(Mp2.m10, c3.x, Mp2.m11 * c3.y)
              + fmaf(Mp3.m10, c4.x, Mp3.m11 * c4.y);

    // block 0: first 4 threads carry the exact A^(16*tid) * x_0 term
    if (blockIdx.x == 0 && tid < HALO_SEG) {
        float X0 = x0p[0], X1 = x0p[1];
        M22 P;
        if      (tid == 0) P = { 1.f, 0.f, 0.f, 1.f };
        else if (tid == 1) P = M;
        else if (tid == 2) P = Mp2;
        else               P = Mp3;
        xi0 += fmaf(P.m00, X0, P.m01 * X1);
        xi1 += fmaf(P.m10, X0, P.m11 * X1);
    }

    // ---- phase 2: rerun from x_in, emit outputs into swizzled LDS ----
    // element i (= 16*tid + j) lives at LDS slot i ^ ((i>>4)&14)
    //   = 16*tid + (j ^ (tid&14)). Even xor-mask keeps (even,odd) slot pairs
    //   adjacent -> copy-out can use 16B reads.
    {
        const int xm = tid & 14;
        float2* lrow = lout + tid * S;
        float x0v = xi0, x1v = xi1;
        #pragma unroll
        for (int j = 0; j < S; ++j) {
            float v0 = fmaf(w00, U0.f[j], fmaf(w01, U1.f[j], bc0));
            float v1 = fmaf(w10, U0.f[j], fmaf(w11, U1.f[j], bc1));
            float n0 = fmaf(a00, x0v, fmaf(a01, x1v, v0));
            float n1 = fmaf(a10, x0v, fmaf(a11, x1v, v1));
            float cc = U0.f[j] * DT.f[j];
            float sn, cs;
            __sincosf(U1.f[j], &sn, &cs);
            lrow[j ^ xm] = make_float2(fmaf(cc, cs, x0v) - n0,
                                       fmaf(cc, sn, x1v) - n1);
            x0v = n0; x1v = n1;
        }
    }
    __syncthreads();

    // ---- coalesced copy-out: 8 x 1KB-per-wave float4 stores ----
    const float4* lo4 = (const float4*)lout;
    float4* og = (float4*)out + (B0 >> 1);
    #pragma unroll
    for (int m = 0; m < 8; ++m) {
        int f    = m * NTHREADS + tid;          // block-local float4 index
        int i0   = f << 1;                      // first float2 element
        int slot = i0 ^ ((i0 >> 4) & 14);       // even; slot+1 holds i0+1
        og[f] = lo4[slot >> 1];
    }
}

extern "C" void kernel_launch(void* const* d_in, const int* in_sizes, int n_in,
                              void* d_out, int out_size, void* d_ws, size_t ws_size,
                              hipStream_t stream) {
    const float* x0p = (const float*)d_in[0];
    const float* u   = (const float*)d_in[1];
    const float* td  = (const float*)d_in[2];
    const float* WA  = (const float*)d_in[3];
    const float* bA  = (const float*)d_in[4];
    const float* WB  = (const float*)d_in[5];
    const float* bB  = (const float*)d_in[6];
    float* outp = (float*)d_out;

    dim3 grid(T_TOTAL / BLOCK_T);   // 1024 blocks = 4/CU resident, 1 round
    dim3 block(NTHREADS);
    pinn_rnn_kernel<<<grid, block, 0, stream>>>(x0p, u, td, WA, bA, WB, bB, outp);
}

// Round 4
// 105.880 us; speedup vs baseline: 1.2187x; 1.0071x over previous
//
#include <hip/hip_runtime.h>

#define T_TOTAL 4194304
#define S 16                       // timesteps per thread (one segment)
#define NTHREADS 256
#define BLOCK_T (NTHREADS * S)     // 4096 timesteps per block
#define HALO_SEG 4                 // 64 warmup steps; ||A^64|| ~ 1e-8
#define NSEG (NTHREADS + HALO_SEG) // 260

struct M22 { float m00, m01, m10, m11; };
__device__ __forceinline__ M22 mmul(const M22& X, const M22& Y) {
    M22 r;
    r.m00 = fmaf(X.m00, Y.m00, X.m01 * Y.m10);
    r.m01 = fmaf(X.m00, Y.m01, X.m01 * Y.m11);
    r.m10 = fmaf(X.m10, Y.m00, X.m11 * Y.m10);
    r.m11 = fmaf(X.m10, Y.m01, X.m11 * Y.m11);
    return r;
}

struct alignas(16) F16 { float f[16]; };

// 16B-slot swizzle inside a 1024-slot (16KB) region: chunk t, quarter o.
// Spreads a wave's 64 ds_read_b128 chunk-reads over all 8 four-bank groups
// (linear layout puts 32 lanes on banks 0-3 -> 4x LDS serialization).
__device__ __forceinline__ int swz(int t, int o) {
    return (t << 2) | (o ^ ((t >> 1) & 3));
}

__global__ __launch_bounds__(NTHREADS, 4)   // LDS 34.8KB -> 4 blocks/CU, 1 round
void pinn_rnn_kernel(const float* __restrict__ x0p,
                     const float* __restrict__ u,
                     const float* __restrict__ td,
                     const float* __restrict__ WA,
                     const float* __restrict__ bA,
                     const float* __restrict__ WB,
                     const float* __restrict__ bB,
                     float* __restrict__ out)
{
    // buf regions: A = buf[0..1023] (u0, later dt, later outputs)
    //              B = buf[1024..2047] (u1, later outputs)
    __shared__ float4 buf[2048];      // 32 KB, reused across phases
    __shared__ float2 lc[NSEG];       // per-segment zero-state response (2 KB)

    const int tid = threadIdx.x;
    const int B0  = blockIdx.x * BLOCK_T;

    const float a00 = WA[0], a01 = WA[1], a10 = WA[2], a11 = WA[3];
    const float w00 = WB[0], w01 = WB[1], w10 = WB[2], w11 = WB[3];
    const float bc0 = bA[0] + bB[0];
    const float bc1 = bA[1] + bB[1];

    const float* u0 = u;
    const float* u1 = u + T_TOTAL;

    // ---- halo loads first (lanes 0-3 only; strided but tiny) ----
    F16 H0, H1;
    float X0 = 0.f, X1 = 0.f;
    const bool halo_owner = (tid < HALO_SEG);
    if (halo_owner) {
        if (blockIdx.x != 0) {
            const float4* h0 = (const float4*)(u0 + B0 - HALO_SEG * S + tid * S);
            const float4* h1 = (const float4*)(u1 + B0 - HALO_SEG * S + tid * S);
            #pragma unroll
            for (int o = 0; o < 4; ++o) { *(float4*)&H0.f[o*4] = h0[o];
                                          *(float4*)&H1.f[o*4] = h1[o]; }
        } else {
            X0 = x0p[0]; X1 = x0p[1];
            #pragma unroll
            for (int o = 0; o < 4; ++o) { *(float4*)&H0.f[o*4] = make_float4(0,0,0,0);
                                          *(float4*)&H1.f[o*4] = make_float4(0,0,0,0); }
        }
    }

    // ---- stage u0 -> region A, u1 -> region B (coalesced, swizzled) ----
    const float4* gu0 = (const float4*)(u0 + B0);
    const float4* gu1 = (const float4*)(u1 + B0);
    #pragma unroll
    for (int m = 0; m < 4; ++m) {
        int f = m * NTHREADS + tid;            // float4 index in block window
        int t = f >> 2, o = f & 3;
        float4 a = gu0[f], b = gu1[f];
        buf[swz(t, o)]        = a;
        buf[1024 + swz(t, o)] = b;
    }

    // ---- powers of A (uniform) ----
    M22 A   = { a00, a01, a10, a11 };
    M22 A2  = mmul(A,  A );
    M22 A4  = mmul(A2, A2);
    M22 A8  = mmul(A4, A4);
    M22 M   = mmul(A8, A8);   // A^16
    M22 Mp2 = mmul(M,  M );   // A^32
    M22 Mp3 = mmul(Mp2, M);   // A^48

    __syncthreads();

    // ---- own-chunk reads: 8 x ds_read_b128, bank-spread by swizzle ----
    F16 U0, U1;
    {
        const int s = (tid >> 1) & 3;
        #pragma unroll
        for (int o = 0; o < 4; ++o) {
            *(float4*)&U0.f[o*4] = buf[(tid << 2) | (o ^ s)];
            *(float4*)&U1.f[o*4] = buf[1024 + ((tid << 2) | (o ^ s))];
        }
    }

    // ---- phase 1: zero-state response c for own segment ----
    {
        float x0v = 0.f, x1v = 0.f;
        #pragma unroll
        for (int j = 0; j < S; ++j) {
            float v0 = fmaf(w00, U0.f[j], fmaf(w01, U1.f[j], bc0));
            float v1 = fmaf(w10, U0.f[j], fmaf(w11, U1.f[j], bc1));
            float n0 = fmaf(a00, x0v, fmaf(a01, x1v, v0));
            float n1 = fmaf(a10, x0v, fmaf(a11, x1v, v1));
            x0v = n0; x1v = n1;
        }
        lc[tid + HALO_SEG] = make_float2(x0v, x1v);
    }
    if (halo_owner) {
        float x0v = 0.f, x1v = 0.f;
        #pragma unroll
        for (int j = 0; j < S; ++j) {
            float v0 = fmaf(w00, H0.f[j], fmaf(w01, H1.f[j], bc0));
            float v1 = fmaf(w10, H0.f[j], fmaf(w11, H1.f[j], bc1));
            float n0 = fmaf(a00, x0v, fmaf(a01, x1v, v0));
            float n1 = fmaf(a10, x0v, fmaf(a11, x1v, v1));
            x0v = n0; x1v = n1;
        }
        if (blockIdx.x == 0) { x0v = 0.f; x1v = 0.f; }  // nothing before t=0
        lc[tid] = make_float2(x0v, x1v);
    }
    __syncthreads();   // lc ready; region A (u0 copy) now dead

    // ---- stage dt -> region A (coalesced, swizzled); overlap x_in calc ----
    const float4* gdt = (const float4*)(td + B0);
    #pragma unroll
    for (int m = 0; m < 4; ++m) {
        int f = m * NTHREADS + tid;
        buf[swz(f >> 2, f & 3)] = gdt[f];
    }

    // x_in = c_{g-1} + M c_{g-2} + M^2 c_{g-3} + M^3 c_{g-4}
    float2 c1 = lc[tid + 3], c2 = lc[tid + 2], c3 = lc[tid + 1], c4 = lc[tid];
    float xi0 = c1.x
              + fmaf(M.m00,   c2.x, M.m01   * c2.y)
              + fmaf(Mp2.m00, c3.x, Mp2.m01 * c3.y)
              + fmaf(Mp3.m00, c4.x, Mp3.m01 * c4.y);
    float xi1 = c1.y
              + fmaf(M.m10,   c2.x, M.m11   * c2.y)
              + fmaf(Mp2.m10, c3.x, Mp2.m11 * c3.y)
              + fmaf(Mp3.m10, c4.x, Mp3.m11 * c4.y);

    if (blockIdx.x == 0 && halo_owner) {   // exact A^(16*tid) * x_0 term
        M22 P;
        if      (tid == 0) P = { 1.f, 0.f, 0.f, 1.f };
        else if (tid == 1) P = M;
        else if (tid == 2) P = Mp2;
        else               P = Mp3;
        xi0 += fmaf(P.m00, X0, P.m01 * X1);
        xi1 += fmaf(P.m10, X0, P.m11 * X1);
    }
    __syncthreads();   // dt staged

    // ---- DT chunk to regs ----
    F16 DT;
    {
        const int s = (tid >> 1) & 3;
        #pragma unroll
        for (int o = 0; o < 4; ++o)
            *(float4*)&DT.f[o*4] = buf[(tid << 2) | (o ^ s)];
    }
    __syncthreads();   // all DT reads done; buf free for outputs

    // ---- phase 2: replay from x_in, write swizzled outputs into buf ----
    // element i = 16*tid + j -> float2 slot i ^ ((i>>4)&14)
    {
        float2* lout = (float2*)buf;
        const int xm = tid & 14;
        float2* lrow = lout + tid * S;
        float x0v = xi0, x1v = xi1;
        #pragma unroll
        for (int j = 0; j < S; ++j) {
            float v0 = fmaf(w00, U0.f[j], fmaf(w01, U1.f[j], bc0));
            float v1 = fmaf(w10, U0.f[j], fmaf(w11, U1.f[j], bc1));
            float n0 = fmaf(a00, x0v, fmaf(a01, x1v, v0));
            float n1 = fmaf(a10, x0v, fmaf(a11, x1v, v1));
            float cc = U0.f[j] * DT.f[j];
            float sn, cs;
            __sincosf(U1.f[j], &sn, &cs);
            lrow[j ^ xm] = make_float2(fmaf(cc, cs, x0v) - n0,
                                       fmaf(cc, sn, x1v) - n1);
            x0v = n0; x1v = n1;
        }
    }
    __syncthreads();

    // ---- coalesced copy-out: 8 x 1KB-per-wave float4 stores ----
    const float4* lo4 = (const float4*)buf;
    float4* og = (float4*)out + (B0 >> 1);
    #pragma unroll
    for (int m = 0; m < 8; ++m) {
        int f    = m * NTHREADS + tid;          // block-local float4 index
        int i0   = f << 1;                      // first float2 element
        int slot = i0 ^ ((i0 >> 4) & 14);       // even; slot+1 holds i0+1
        og[f] = lo4[slot >> 1];
    }
}

extern "C" void kernel_launch(void* const* d_in, const int* in_sizes, int n_in,
                              void* d_out, int out_size, void* d_ws, size_t ws_size,
                              hipStream_t stream) {
    const float* x0p = (const float*)d_in[0];
    const float* u   = (const float*)d_in[1];
    const float* td  = (const float*)d_in[2];
    const float* WA  = (const float*)d_in[3];
    const float* bA  = (const float*)d_in[4];
    const float* WB  = (const float*)d_in[5];
    const float* bB  = (const float*)d_in[6];
    float* outp = (float*)d_out;

    dim3 grid(T_TOTAL / BLOCK_T);   // 1024 blocks = 4/CU resident, 1 round
    dim3 block(NTHREADS);
    pinn_rnn_kernel<<<grid, block, 0, stream>>>(x0p, u, td, WA, bA, WB, bB, outp);
}